// Round 5
// baseline (534.524 us; speedup 1.0000x reference)
//
#include <hip/hip_runtime.h>

typedef _Float16 f16;
typedef __attribute__((ext_vector_type(8))) _Float16 f16x8;
typedef __attribute__((ext_vector_type(8))) short s16x8;
typedef __attribute__((ext_vector_type(4))) float f32x4;
typedef __attribute__((ext_vector_type(4))) unsigned short us16x4;

#define DIN   1024
#define DD    128
#define NBAT  4
#define TLEN  4096

// ---------- scalar conversions ----------
static __device__ __forceinline__ unsigned short f2bf(float f) {
  unsigned int u = __builtin_bit_cast(unsigned int, f);
  u = (u + 0x7fffu + ((u >> 16) & 1u)) >> 16;
  return (unsigned short)u;
}
static __device__ __forceinline__ float bf2f(unsigned short h) {
  return __builtin_bit_cast(float, (unsigned int)h << 16);
}
static __device__ __forceinline__ unsigned short f2h(float f) {
  _Float16 h = (_Float16)f;
  return __builtin_bit_cast(unsigned short, h);
}
// 128-elem row swizzle: 16B granules XORed by key (bank-conflict-free LDS reads)
static __device__ __forceinline__ int swz128(int d, int key) {
  return ((((d >> 3) ^ key) & 15) << 3) | (d & 7);
}

// ---------- async global->LDS, width 16 ----------
typedef __attribute__((address_space(1))) const unsigned int* gas1_t;
typedef __attribute__((address_space(3))) unsigned int* las3_t;
static __device__ __forceinline__ void gload16(const void* g, void* l) {
  __builtin_amdgcn_global_load_lds((gas1_t)g, (las3_t)l, 16, 0, 0);
}

// =====================================================================
// Kernel 1: W' = bf16 hi/lo of [Wq|Wk|Wv]^T, plain layout [col 0..383][DIN].
// =====================================================================
__global__ void build_wt(const float* __restrict__ Wq, const float* __restrict__ Wk,
                         const float* __restrict__ Wv,
                         unsigned short* __restrict__ Wh, unsigned short* __restrict__ Wl) {
  int col = blockIdx.x;                 // 0..383
  const float* W = (col < 128) ? Wq : (col < 256 ? Wk : Wv);
  int j = col & 127;
  for (int kk = (int)threadIdx.x; kk < DIN; kk += blockDim.x) {
    float w = W[(size_t)kk * DD + j];
    unsigned short h = f2bf(w);
    unsigned short l = f2bf(w - bf2f(h));
    Wh[(size_t)col * DIN + kk] = h;
    Wl[(size_t)col * DIN + kk] = l;
  }
}

// =====================================================================
// Kernel 2: projection GEMM C[16384][384] = x @ W' (bf16 hi/lo 3-product).
// 512 blocks x 32 rows, 4 waves (each 32 rows x 96 cols). x converted
// fp32->bf16 hi/lo ONCE per 64-K chunk into a small swizzled LDS tile
// (fused cast; no separate xcast pass). W' fragments direct from L2.
// q plain [t][d]; k swizzled rows (for gload_lds consumer); v plain [n][d][t].
// =====================================================================
__global__ __launch_bounds__(256, 2) void proj_qkv(
    const float* __restrict__ x,
    const unsigned short* __restrict__ Wh, const unsigned short* __restrict__ Wl,
    unsigned short* __restrict__ qws, unsigned short* __restrict__ kws,
    unsigned short* __restrict__ vws) {
  __shared__ __align__(16) unsigned short Ah[32 * 64];
  __shared__ __align__(16) unsigned short Al[32 * 64];
  __shared__ __align__(16) unsigned short vt[128 * 40];

  const int tid = (int)threadIdx.x;
  const int lane = tid & 63;
  const int wid = tid >> 6;
  const int lr = lane & 15;
  const int lg = lane >> 4;
  const int t0 = blockIdx.x * 32;

  const int srow = tid >> 3;            // staging: row 0..31
  const int sg = tid & 7;               // granule 0..7 (8 elems)
  const float* xsrc = x + (size_t)(t0 + srow) * DIN + sg * 8;
  const int sgs = (sg ^ (srow & 7)) * 8;

  f32x4 acc[2][6];
#pragma unroll
  for (int a = 0; a < 2; ++a)
#pragma unroll
    for (int c = 0; c < 6; ++c) acc[a][c] = f32x4{0.f, 0.f, 0.f, 0.f};

  for (int kr = 0; kr < 16; ++kr) {
    // ---- stage x[32][64] -> hi/lo bf16 LDS (swizzled granules) ----
    {
      f32x4 a0 = *(const f32x4*)(xsrc + kr * 64);
      f32x4 a1 = *(const f32x4*)(xsrc + kr * 64 + 4);
      s16x8 hv, lv;
#pragma unroll
      for (int e = 0; e < 4; ++e) {
        unsigned short h0 = f2bf(a0[e]);
        hv[e] = (short)h0; lv[e] = (short)f2bf(a0[e] - bf2f(h0));
        unsigned short h1 = f2bf(a1[e]);
        hv[4 + e] = (short)h1; lv[4 + e] = (short)f2bf(a1[e] - bf2f(h1));
      }
      *(s16x8*)&Ah[srow * 64 + sgs] = hv;
      *(s16x8*)&Al[srow * 64 + sgs] = lv;
    }
    __syncthreads();

#pragma unroll
    for (int kc = 0; kc < 2; ++kc) {
      s16x8 ah[2], al[2];
#pragma unroll
      for (int rf = 0; rf < 2; ++rf) {
        int g = (((kc * 4 + lg) ^ (lr & 7)) << 3);
        ah[rf] = *(const s16x8*)&Ah[(rf * 16 + lr) * 64 + g];
        al[rf] = *(const s16x8*)&Al[(rf * 16 + lr) * 64 + g];
      }
#pragma unroll
      for (int cf = 0; cf < 6; ++cf) {
        size_t boff = (size_t)(wid * 96 + cf * 16 + lr) * DIN + (size_t)kr * 64 + kc * 32 + lg * 8;
        s16x8 bh = *(const s16x8*)(Wh + boff);
        s16x8 bl = *(const s16x8*)(Wl + boff);
#pragma unroll
        for (int rf = 0; rf < 2; ++rf) {
          acc[rf][cf] = __builtin_amdgcn_mfma_f32_16x16x32_bf16(ah[rf], bh, acc[rf][cf], 0, 0, 0);
          acc[rf][cf] = __builtin_amdgcn_mfma_f32_16x16x32_bf16(ah[rf], bl, acc[rf][cf], 0, 0, 0);
          acc[rf][cf] = __builtin_amdgcn_mfma_f32_16x16x32_bf16(al[rf], bh, acc[rf][cf], 0, 0, 0);
        }
      }
    }
    __syncthreads();
  }

  const int n = t0 >> 12, t0l = t0 & (TLEN - 1);
#pragma unroll
  for (int cf = 0; cf < 6; ++cf) {
    int c = wid * 96 + cf * 16 + lr;
#pragma unroll
    for (int rf = 0; rf < 2; ++rf)
#pragma unroll
      for (int e = 0; e < 4; ++e) {
        int tl = rf * 16 + lg * 4 + e;           // 0..31
        int t = t0 + tl;
        unsigned short hv = f2h(acc[rf][cf][e]);
        if (c < 128) {
          qws[(size_t)t * DD + c] = hv;                       // plain
        } else if (c < 256) {
          kws[(size_t)t * DD + swz128(c - 128, t & 7)] = hv;  // row-swizzled
        } else {
          vt[(c - 256) * 40 + tl] = hv;
        }
      }
  }
  __syncthreads();
  if (tid < 128) {
    int d = tid;
    unsigned short* dst = vws + ((size_t)n * DD + d) * TLEN + t0l;
#pragma unroll
    for (int h = 0; h < 4; ++h) {
      f16x8 vv = *(const f16x8*)&vt[d * 40 + h * 8];
      *(f16x8*)(dst + h * 8) = vv;                            // plain [d][t]
    }
  }
}

// =====================================================================
// Kernel 3: fused causal attention. 512 blocks x 512 thr (8 waves),
// 32-row q-tiles, cr-balanced mapping, per-block upper-triangle zero-fill.
// k LDS double-buffered, prefetched ONE TILE AHEAD (issued at top of the
// previous tile's compute -> the single per-tile __syncthreads drains
// mostly-retired ops). v read DIRECT from global (plain [n][d][t], 64B
// coalesced L2 hits) - no v staging, no v ds_reads. p-bounce wave-private.
// =====================================================================
__global__ __launch_bounds__(512, 4) void attn_fused(
    const unsigned short* __restrict__ qws, const unsigned short* __restrict__ kws,
    const unsigned short* __restrict__ vws, float* __restrict__ out,
    float* __restrict__ att) {
  __shared__ __align__(16) unsigned short kl[2][16384];   // 2 x 32KB k tiles
  __shared__ __align__(16) unsigned short pp[8][16 * 40]; // wave-private p
  __shared__ float zb[8][16];
  __shared__ float rzb[32];

  const int tid = (int)threadIdx.x;
  const int lane = tid & 63;
  const int wid = tid >> 6;
  const int lr = lane & 15;
  const int lg = lane >> 4;
  const int rg = wid >> 2;              // row group (0/1): rows rg*16
  const int cg = wid & 3;               // col group: cols cg*32 of 128-tile

  int b = (int)blockIdx.x;
  int cr = (b < 256) ? b : (767 - b);
  const int qi = cr >> 2;               // 0..127
  const int n = cr & 3;
  const int t0 = qi * 32;
  const int jmax = (t0 + 31) >> 7;

  const unsigned short* kbase = kws + (size_t)(n * TLEN) * DD;
  const unsigned short* vbase = vws + (size_t)n * DD * TLEN;
  float* attn_base = att + (size_t)n * TLEN * TLEN + (size_t)t0 * TLEN;

  // ---- prefetch k tile 0 into kl[0] ----
#pragma unroll
  for (int rr = 0; rr < 4; ++rr) {
    int idx = rr * 512 + tid;
    gload16((const char*)kbase + (size_t)idx * 16, (char*)kl[0] + (size_t)idx * 16);
  }

  // ---- zero-fill this block's own upper region ----
  {
    int cz0 = (jmax + 1) * 128;
    f32x4 zv = f32x4{0.f, 0.f, 0.f, 0.f};
    for (int r = 0; r < 32; ++r) {
      float* rowp = attn_base + (size_t)r * TLEN;
      for (int c = cz0 + tid * 4; c < TLEN; c += 2048) *(f32x4*)(rowp + c) = zv;
    }
  }

  // ---- q A-fragments (plain layout, direct global) ----
  f16x8 qa[4];
  {
    const unsigned short* q0 = qws + (size_t)(n * TLEN + t0 + rg * 16 + lr) * DD + lg * 8;
#pragma unroll
    for (int kc = 0; kc < 4; ++kc) qa[kc] = *(const f16x8*)(q0 + kc * 32);
  }
  const int rowl0 = rg * 16 + lg * 4;

  // ================= Phase A: row sums Z =================
  float zacc[4] = {0.f, 0.f, 0.f, 0.f};
  for (int j = 0; j <= jmax; ++j) {
    __syncthreads();                    // kl[j&1] complete (own vmcnt drained + barrier)
    if (j < jmax) {
      const char* gk = (const char*)(kbase + (size_t)((j + 1) * 128) * DD);
#pragma unroll
      for (int rr = 0; rr < 4; ++rr) {
        int idx = rr * 512 + tid;
        gload16(gk + (size_t)idx * 16, (char*)kl[(j + 1) & 1] + (size_t)idx * 16);
      }
    }
    const unsigned short* klc = kl[j & 1];
#pragma unroll
    for (int cf = 0; cf < 2; ++cf) {
      int krow = cg * 32 + cf * 16 + lr;
      f32x4 s = f32x4{0.f, 0.f, 0.f, 0.f};
#pragma unroll
      for (int kc = 0; kc < 4; ++kc) {
        f16x8 kb = *(const f16x8*)&klc[krow * 128 + ((((kc * 4 + lg) ^ (krow & 7))) << 3)];
        s = __builtin_amdgcn_mfma_f32_16x16x32_f16(qa[kc], kb, s, 0, 0, 0);
      }
      int colg = j * 128 + krow;
#pragma unroll
      for (int e = 0; e < 4; ++e) {
        int rowg = t0 + rowl0 + e;
        zacc[e] += (colg <= rowg && s[e] != 0.0f) ? __expf(s[e]) : 0.0f;
      }
    }
  }
#pragma unroll
  for (int e = 0; e < 4; ++e) {
    float z = zacc[e];
    z += __shfl_xor(z, 1);
    z += __shfl_xor(z, 2);
    z += __shfl_xor(z, 4);
    z += __shfl_xor(z, 8);
    if (lr == 0) zb[wid][lg * 4 + e] = z;
  }
  __syncthreads();
  if (tid < 32) {
    int r = tid, rgq = r >> 4, rl = r & 15;
    float z = zb[rgq * 4 + 0][rl] + zb[rgq * 4 + 1][rl] + zb[rgq * 4 + 2][rl] + zb[rgq * 4 + 3][rl];
    rzb[r] = (z > 0.f) ? (1.0f / z) : 0.0f;
  }
  __syncthreads();
  float rz[4];
#pragma unroll
  for (int e = 0; e < 4; ++e) rz[e] = rzb[rowl0 + e];

  // ---- prefetch k tile 0 again for phase B (safe: all reads done) ----
#pragma unroll
  for (int rr = 0; rr < 4; ++rr) {
    int idx = rr * 512 + tid;
    gload16((const char*)kbase + (size_t)idx * 16, (char*)kl[0] + (size_t)idx * 16);
  }

  // ================= Phase B =================
  f32x4 oacc[8];
#pragma unroll
  for (int fd = 0; fd < 8; ++fd) oacc[fd] = f32x4{0.f, 0.f, 0.f, 0.f};
  unsigned short* ppw = pp[wid];

  for (int j = 0; j <= jmax; ++j) {
    __syncthreads();                    // kl[j&1] ready
    if (j < jmax) {
      const char* gk = (const char*)(kbase + (size_t)((j + 1) * 128) * DD);
#pragma unroll
      for (int rr = 0; rr < 4; ++rr) {
        int idx = rr * 512 + tid;
        gload16(gk + (size_t)idx * 16, (char*)kl[(j + 1) & 1] + (size_t)idx * 16);
      }
    }
    const unsigned short* klc = kl[j & 1];

    // QK (bitwise identical to phase A)
    f32x4 s[2];
#pragma unroll
    for (int cf = 0; cf < 2; ++cf) {
      int krow = cg * 32 + cf * 16 + lr;
      s[cf] = f32x4{0.f, 0.f, 0.f, 0.f};
#pragma unroll
      for (int kc = 0; kc < 4; ++kc) {
        f16x8 kb = *(const f16x8*)&klc[krow * 128 + ((((kc * 4 + lg) ^ (krow & 7))) << 3)];
        s[cf] = __builtin_amdgcn_mfma_f32_16x16x32_f16(qa[kc], kb, s[cf], 0, 0, 0);
      }
    }

    // v fragments direct from global (issued early; latency hides under exp/stores)
    f16x8 vb[8];
#pragma unroll
    for (int fd = 0; fd < 8; ++fd) {
      vb[fd] = *(const f16x8*)(vbase + (size_t)(fd * 16 + lr) * TLEN + (size_t)j * 128 + cg * 32 + lg * 8);
    }

    // exp, att store, wave-private p
#pragma unroll
    for (int cf = 0; cf < 2; ++cf) {
      int krow = cg * 32 + cf * 16 + lr;
      int colg = j * 128 + krow;
#pragma unroll
      for (int e = 0; e < 4; ++e) {
        int rowg = t0 + rowl0 + e;
        float ev = (colg <= rowg && s[cf][e] != 0.0f) ? __expf(s[cf][e]) : 0.0f;
        float p = ev * rz[e];
        attn_base[(size_t)(rowl0 + e) * TLEN + colg] = p;
        ppw[(lg * 4 + e) * 40 + cf * 16 + lr] = f2h(p);
      }
    }
    // wave-synchronous p read (A-layout) - lgkmcnt only, no barrier
    f16x8 pa = *(const f16x8*)&ppw[lr * 40 + lg * 8];
    // PV: this wave's K=32 slice, all 128 d
#pragma unroll
    for (int fd = 0; fd < 8; ++fd) {
      oacc[fd] = __builtin_amdgcn_mfma_f32_16x16x32_f16(pa, vb[fd], oacc[fd], 0, 0, 0);
    }
  }

  // ---- cross-wave PV reduction (reuse k LDS as 8x16x128 f32 = 64KB) ----
  __syncthreads();
  float* red = (float*)kl;
#pragma unroll
  for (int fd = 0; fd < 8; ++fd)
#pragma unroll
    for (int e = 0; e < 4; ++e)
      red[((size_t)wid * 16 + lg * 4 + e) * 128 + fd * 16 + lr] = oacc[fd][e];
  __syncthreads();
  {
    int r = tid >> 4;                   // 0..31
    int d0 = (tid & 15) * 8;
    int rgq = r >> 4, rl = r & 15;
    f32x4 s0 = f32x4{0.f, 0.f, 0.f, 0.f}, s1 = f32x4{0.f, 0.f, 0.f, 0.f};
#pragma unroll
    for (int c = 0; c < 4; ++c) {
      const float* src = red + ((size_t)(rgq * 4 + c) * 16 + rl) * 128 + d0;
      f32x4 a = *(const f32x4*)src;
      f32x4 bb = *(const f32x4*)(src + 4);
#pragma unroll
      for (int i = 0; i < 4; ++i) { s0[i] += a[i]; s1[i] += bb[i]; }
    }
    float* dst = out + ((size_t)n * TLEN + t0 + r) * DD + d0;
    *(f32x4*)dst = s0;
    *(f32x4*)(dst + 4) = s1;
  }
}

// =====================================================================
extern "C" void kernel_launch(void* const* d_in, const int* in_sizes, int n_in,
                              void* d_out, int out_size, void* d_ws, size_t ws_size,
                              hipStream_t stream) {
  const float* x  = (const float*)d_in[0];
  const float* Wq = (const float*)d_in[1];
  const float* Wk = (const float*)d_in[2];
  const float* Wv = (const float*)d_in[3];

  float* out = (float*)d_out;                              // [4,4096,128]
  float* att = out + (size_t)NBAT * TLEN * DD;             // [4,4096,4096]

  unsigned short* ws = (unsigned short*)d_ws;
  unsigned short* Wh  = ws;                                // 384*1024
  unsigned short* Wl  = Wh + (size_t)384 * DIN;
  unsigned short* qws = Wl + (size_t)384 * DIN;            // 16384*128 f16 [t][d] plain
  unsigned short* kws = qws + (size_t)NBAT * TLEN * DD;    // swizzled rows
  unsigned short* vws = kws + (size_t)NBAT * TLEN * DD;    // [4][128][4096] plain

  build_wt<<<dim3(384), dim3(256), 0, stream>>>(Wq, Wk, Wv, Wh, Wl);
  proj_qkv<<<dim3(512), dim3(256), 0, stream>>>(x, Wh, Wl, qws, kws, vws);
  attn_fused<<<dim3(512), dim3(512), 0, stream>>>(qws, kws, vws, out, att);
}